// Round 6
// baseline (473.927 us; speedup 1.0000x reference)
//
#include <hip/hip_runtime.h>
#include <hip/hip_bf16.h>

typedef short bf16x8 __attribute__((ext_vector_type(8)));
typedef float f32x16 __attribute__((ext_vector_type(16)));

__device__ __forceinline__ unsigned short f2bf(float x) {
    unsigned u = __float_as_uint(x);
    return (unsigned short)((u + 0x7FFFu + ((u >> 16) & 1u)) >> 16);
}
__device__ __forceinline__ float bf2f(unsigned short h) {
    return __uint_as_float(((unsigned)h) << 16);
}
__device__ __forceinline__ unsigned score_key(float s) {
    unsigned u = __float_as_uint(s);
    return (u & 0x80000000u) ? ~u : (u | 0x80000000u);
}

// native-cast split: f32[8] -> bf16 hi + bf16 lo
__device__ __forceinline__ void split8n(const float4& fa, const float4& fb,
                                        bf16x8& hv, bf16x8& lv) {
    const float f[8] = {fa.x, fa.y, fa.z, fa.w, fb.x, fb.y, fb.z, fb.w};
    union { unsigned short u[8]; bf16x8 v; } H, L;
#pragma unroll
    for (int j = 0; j < 8; ++j) {
        __hip_bfloat16 hb = __float2bfloat16(f[j]);
        const unsigned short hr = reinterpret_cast<const unsigned short&>(hb);
        const float hf = __uint_as_float(((unsigned)hr) << 16);
        __hip_bfloat16 lb = __float2bfloat16(f[j] - hf);
        H.u[j] = hr;
        L.u[j] = reinterpret_cast<const unsigned short&>(lb);
    }
    hv = H.v; lv = L.v;
}

// v[j] = sum_o W2[j,o]*Ws[o];  v[256] = dot(b2,Ws) + bs
__global__ void prep_kernel(const float* __restrict__ W2, const float* __restrict__ b2,
                            const float* __restrict__ Ws, const float* __restrict__ bs,
                            float* __restrict__ v, int OUT) {
    int j = threadIdx.x;
    float acc = 0.f;
    for (int o = 0; o < OUT; ++o) acc += W2[j * OUT + o] * Ws[o];
    v[j] = acc;
    if (j == 0) {
        float c = bs[0];
        for (int o = 0; o < OUT; ++o) c += b2[o] * Ws[o];
        v[256] = c;
    }
}

// W1 [256][256] -> 32x32x16 fragment pack, hi/lo (identical layout — absmax-0 verified)
// uint4 idx = kt*2048 + (hl*16 + nt*2 + kc)*64 + lane
// elem j of slot = W1[kt*32 + kc*16 + (lane>>5)*8 + j][nt*32 + (lane&31)]
__global__ void prep_w1frag(const float* __restrict__ W1, uint4* __restrict__ wfrag) {
    const int s = blockIdx.x * 256 + threadIdx.x;   // 0..16383
    const int kt = s >> 11;
    const int c = (s >> 6) & 31;
    const int lane = s & 63;
    const int hl = c >> 4;
    const int nt = (c >> 1) & 7;
    const int kc = c & 1;
    const int col = nt * 32 + (lane & 31);
    const int k0 = kt * 32 + kc * 16 + (lane >> 5) * 8;
    unsigned pk[4];
#pragma unroll
    for (int q = 0; q < 4; ++q) {
        float x0 = W1[(size_t)(k0 + 2 * q) * 256 + col];
        float x1 = W1[(size_t)(k0 + 2 * q + 1) * 256 + col];
        unsigned short a0, a1;
        if (hl == 0) { a0 = f2bf(x0); a1 = f2bf(x1); }
        else {
            a0 = f2bf(x0 - bf2f(f2bf(x0)));
            a1 = f2bf(x1 - bf2f(f2bf(x1)));
        }
        pk[q] = (unsigned)a0 | ((unsigned)a1 << 16);
    }
    wfrag[s] = make_uint4(pk[0], pk[1], pk[2], pk[3]);
}

__global__ void init_bins(unsigned long long* __restrict__ bins, int n) {
    int i = blockIdx.x * blockDim.x + threadIdx.x;
    if (i < n) bins[i] = 0ULL;
}

// B fragment loader: slot s -> kc = s>>1, g = s&1 (4 nt-chunks, hi+lo)
__device__ __forceinline__ void loadB(const uint4* __restrict__ bk, const int slot,
                                      uint4 bh[4], uint4 bl[4]) {
    const int kc = slot >> 1, g = slot & 1;
#pragma unroll
    for (int j = 0; j < 4; ++j) {
        const int nt = g * 4 + j;
        bh[j] = bk[(nt * 2 + kc) * 64];
        bl[j] = bk[(16 + nt * 2 + kc) * 64];
    }
}

__device__ __forceinline__ void mfma16(f32x16 acc[8], const int g,
                                       const bf16x8 ah, const bf16x8 al,
                                       const uint4 bh[4], const uint4 bl[4]) {
#pragma unroll
    for (int j = 0; j < 4; ++j) {
        const int nt = g * 4 + j;
        const bf16x8 bhv = *(const bf16x8*)&bh[j];
        acc[nt] = __builtin_amdgcn_mfma_f32_32x32x16_bf16(ah, bhv, acc[nt], 0, 0, 0);
        acc[nt] = __builtin_amdgcn_mfma_f32_32x32x16_bf16(al, bhv, acc[nt], 0, 0, 0);
        const bf16x8 blv = *(const bf16x8*)&bl[j];
        acc[nt] = __builtin_amdgcn_mfma_f32_32x32x16_bf16(ah, blv, acc[nt], 0, 0, 0);
        acc[nt] = __builtin_amdgcn_mfma_f32_32x32x16_bf16(al, blv, acc[nt], 0, 0, 0);
    }
}

// Barrier-free, LDS-free: 4 independent waves/block, wave = 32 rows x 256 cols.
// A direct from global (per-lane row), B direct from L2-resident wfrag (coalesced).
__global__ __launch_bounds__(256, 2) void score_kernel(
    const float* __restrict__ desc, const float* __restrict__ kpts,
    const uint4* __restrict__ wfrag,
    const float* __restrict__ b1, const float* __restrict__ g1, const float* __restrict__ be1,
    const int* __restrict__ Hp, const int* __restrict__ Wp,
    const float* __restrict__ v,
    float* __restrict__ scores, unsigned long long* __restrict__ bins,
    int N, int total)
{
    const int t = threadIdx.x;
    const int lane = t & 63;
    const int w = t >> 6;                 // wave 0..3 (independent)
    const int c31 = lane & 31;
    const int h = lane >> 5;
    const int R0 = blockIdx.x * 128 + w * 32;

    // A: lane's row; k-slots of chunk kc: kt*32 + kc*16 + h*8 + {0..7}
    const int rA = min(R0 + c31, total - 1);
    const float* pa = desc + (size_t)rA * 256 + h * 8;

    f32x16 acc[8];
#pragma unroll
    for (int nt = 0; nt < 8; ++nt) {
        const float bc = b1[nt * 32 + c31];     // fold b1 into acc init (col-constant)
#pragma unroll
        for (int r = 0; r < 16; ++r) acc[nt][r] = bc;
    }

    const uint4* bbase = wfrag + lane;
    float4 cA0 = *(const float4*)(pa + 0);
    float4 cA1 = *(const float4*)(pa + 4);
    float4 cA2 = *(const float4*)(pa + 16);
    float4 cA3 = *(const float4*)(pa + 20);

    for (int kt = 0; kt < 8; ++kt) {
        const uint4* bk = bbase + (size_t)kt * 2048;
        // prefetch next-kt A (no barrier anywhere -> stays in flight freely)
        float4 nA0, nA1, nA2, nA3;
        if (kt < 7) {
            const float* pn = pa + (kt + 1) * 32;
            nA0 = *(const float4*)(pn + 0);
            nA1 = *(const float4*)(pn + 4);
            nA2 = *(const float4*)(pn + 16);
            nA3 = *(const float4*)(pn + 20);
        }
        bf16x8 ah0, al0, ah1, al1;
        split8n(cA0, cA1, ah0, al0);
        split8n(cA2, cA3, ah1, al1);
        {
            uint4 bh[4], bl[4];
            loadB(bk, 0, bh, bl); mfma16(acc, 0, ah0, al0, bh, bl);
        }
        {
            uint4 bh[4], bl[4];
            loadB(bk, 1, bh, bl); mfma16(acc, 1, ah0, al0, bh, bl);
        }
        {
            uint4 bh[4], bl[4];
            loadB(bk, 2, bh, bl); mfma16(acc, 0, ah1, al1, bh, bl);
        }
        {
            uint4 bh[4], bl[4];
            loadB(bk, 3, bh, bl); mfma16(acc, 1, ah1, al1, bh, bl);
        }
        cA0 = nA0; cA1 = nA1; cA2 = nA2; cA3 = nA3;
    }

    // ---- in-wave epilogue. C/D: rowIn32=(reg&3)+8*(reg>>2)+4*h, col=nt*32+c31
    float gE[8], beE[8], vE[8];
#pragma unroll
    for (int nt = 0; nt < 8; ++nt) {
        const int c = nt * 32 + c31;
        gE[nt] = g1[c]; beE[nt] = be1[c]; vE[nt] = v[c];
    }
    const float Wf = (float)Wp[0];
    const int Hi = Hp[0];
    const float t02 = (float)(0.2 * (double)Hi);
    const float t05 = (float)(0.5 * (double)Hi);
    const float t03 = (float)(0.3 * (double)Hi);
    const float cterm = v[256];

#pragma unroll
    for (int reg = 0; reg < 16; ++reg) {
        float sx = 0.f, sq = 0.f;
#pragma unroll
        for (int nt = 0; nt < 8; ++nt) {
            const float x = acc[nt][reg];
            sx += x; sq = fmaf(x, x, sq);
        }
#pragma unroll
        for (int m = 1; m <= 16; m <<= 1) {
            sx += __shfl_xor(sx, m);
            sq += __shfl_xor(sq, m);
        }
        const float mu = sx * (1.f / 256.f);
        const float var = sq * (1.f / 256.f) - mu * mu;
        const float rs = 1.f / sqrtf(var + 1e-5f);
        float dot = 0.f;
#pragma unroll
        for (int nt = 0; nt < 8; ++nt) {
            const float hv = (acc[nt][reg] - mu) * rs * gE[nt] + beE[nt];
            const float sg = 1.f / (1.f + __expf(-hv));
            dot = fmaf(vE[nt], hv * sg, dot);
        }
#pragma unroll
        for (int m = 1; m <= 16; m <<= 1) dot += __shfl_xor(dot, m);

        if (c31 == 0) {
            const int row = R0 + (reg & 3) + 8 * (reg >> 2) + 4 * h;
            if (row < total) {
                const float sc = dot + cterm;
                scores[row] = sc;
                const float x = kpts[(size_t)row * 2 + 0];
                const float y = kpts[(size_t)row * 2 + 1];
                int g = -1;
                if (y > t05) {
                    int bgx = (int)(x / Wf * 16.f); bgx = min(max(bgx, 0), 15);
                    int bgy = (int)((y - t05) / t05 * 6.f); bgy = min(max(bgy, 0), 5);
                    g = 32 + bgy * 16 + bgx;
                } else if (y > t02) {
                    int mgx = (int)(x / Wf * 8.f); mgx = min(max(mgx, 0), 7);
                    int mgy = (int)((y - t02) / t03 * 4.f); mgy = min(max(mgy, 0), 3);
                    g = mgy * 8 + mgx;
                }
                if (g >= 0) {
                    const int bb = row / N;
                    const int n = row - bb * N;
                    const unsigned long long pk =
                        ((unsigned long long)score_key(sc) << 32) | (unsigned)(~(unsigned)n);
                    atomicMax(&bins[bb * 128 + g], pk);
                }
            }
        }
    }
}

// One block per batch: compact bin winners (bin order), top-k fallback, gather outputs.
__global__ __launch_bounds__(256) void finalize_kernel(
    const float* __restrict__ scores, const unsigned long long* __restrict__ bins,
    const float* __restrict__ desc, const float* __restrict__ kpts,
    const int* __restrict__ tkp, float* __restrict__ out, int B, int N)
{
    const int b = blockIdx.x, t = threadIdx.x;
    const int topk = tkp[0];
    __shared__ int selL[512];
    __shared__ int nselS;
    __shared__ unsigned long long red[256];
    __shared__ unsigned long long binL[128];

    if (t < 128) binL[t] = bins[b * 128 + t];
    __syncthreads();
    if (t == 0) {
        int c = 0;
        for (int i = 0; i < 128; ++i)
            if ((binL[i] >> 32) != 0ULL) selL[c++] = (int)(~(unsigned)binL[i]);
        nselS = c;
    }
    __syncthreads();
    const int nsel = nselS;

    for (int need = nsel; need < topk; ++need) {
        unsigned long long best = 0ULL;
        for (int i = t; i < N; i += 256) {
            bool taken = false;
            for (int s2 = 0; s2 < need; ++s2)
                if (selL[s2] == i) { taken = true; break; }
            if (!taken) {
                const unsigned long long pk =
                    ((unsigned long long)score_key(scores[(size_t)b * N + i]) << 32)
                    | (unsigned)(~(unsigned)i);
                if (pk > best) best = pk;
            }
        }
        red[t] = best;
        __syncthreads();
        for (int off = 128; off > 0; off >>= 1) {
            if (t < off) { if (red[t + off] > red[t]) red[t] = red[t + off]; }
            __syncthreads();
        }
        if (t == 0) selL[need] = (int)(~(unsigned)red[0]);
        __syncthreads();
    }

    float* o_feat = out;
    float* o_kpts = out + (size_t)B * topk * 256;
    float* o_idx  = out + (size_t)B * topk * 258;
    for (int e = t; e < topk * 64; e += 256) {
        const int j = e >> 6, q4 = e & 63;
        const int n = selL[j];
        *(float4*)&o_feat[((size_t)b * topk + j) * 256 + q4 * 4] =
            *(const float4*)&desc[((size_t)b * N + n) * 256 + q4 * 4];
    }
    for (int j = t; j < topk; j += 256) {
        const int n = selL[j];
        o_kpts[((size_t)b * topk + j) * 2 + 0] = kpts[((size_t)b * N + n) * 2 + 0];
        o_kpts[((size_t)b * topk + j) * 2 + 1] = kpts[((size_t)b * N + n) * 2 + 1];
        o_idx[(size_t)b * topk + j] = (float)n;
    }
}

extern "C" void kernel_launch(void* const* d_in, const int* in_sizes, int n_in,
                              void* d_out, int out_size, void* d_ws, size_t ws_size,
                              hipStream_t stream) {
    const float* kpts = (const float*)d_in[0];
    const float* desc = (const float*)d_in[1];
    const int*   Hp   = (const int*)d_in[2];
    const int*   Wp   = (const int*)d_in[3];
    const int*   tkp  = (const int*)d_in[4];
    const float* W1   = (const float*)d_in[5];
    const float* b1   = (const float*)d_in[6];
    const float* g1   = (const float*)d_in[7];
    const float* be1  = (const float*)d_in[8];
    const float* W2   = (const float*)d_in[9];
    const float* b2   = (const float*)d_in[10];
    const float* Ws   = (const float*)d_in[11];
    const float* bs   = (const float*)d_in[12];

    const int total = in_sizes[1] / 256;   // B*N
    const int BT    = out_size / 259;      // B*topk
    const int B     = BT / 128;            // topk = 128 for this problem
    const int N     = total / B;
    const int OUT   = in_sizes[11];        // 128

    float* ws_v      = (float*)d_ws;                       // 257 floats (pad 512)
    float* ws_scores = ws_v + 512;                         // total floats
    size_t off = ((size_t)(512 + total) * 4 + 255) & ~(size_t)255;
    unsigned long long* ws_bins = (unsigned long long*)((char*)d_ws + off);
    size_t off2 = (off + (size_t)B * 128 * 8 + 255) & ~(size_t)255;
    uint4* ws_wfrag = (uint4*)((char*)d_ws + off2);        // 16384 uint4 = 256KB

    prep_kernel<<<1, 256, 0, stream>>>(W2, b2, Ws, bs, ws_v, OUT);
    prep_w1frag<<<64, 256, 0, stream>>>(W1, ws_wfrag);
    init_bins<<<(B * 128 + 255) / 256, 256, 0, stream>>>(ws_bins, B * 128);
    score_kernel<<<(total + 127) / 128, 256, 0, stream>>>(
        desc, kpts, ws_wfrag, b1, g1, be1, Hp, Wp, ws_v, ws_scores, ws_bins, N, total);
    finalize_kernel<<<B, 256, 0, stream>>>(ws_scores, ws_bins, desc, kpts, tkp,
                                           (float*)d_out, B, N);
}